// Round 9
// baseline (267.620 us; speedup 1.0000x reference)
//
#include <hip/hip_runtime.h>
#include <math.h>

#define LL 128                  // sequence length
#define LP 129                  // padded row stride (floats)
#define TCR 144                 // tC rows incl. guard (wide-path rows reach 142)
#define TC_SZ (TCR * LP)        // 18576 floats
#define TI_SZ (LL * LP + 160)   // 16672 floats (col overshoot reads)
#define NT 512
#define NW 8

#define LOG2E 1.4426950408889634f
#define LN2   0.6931471805599453f

// DPP quad butterfly (lanes bits 0-1); ctrl compile-time constant.
template <int CTRL>
__device__ __forceinline__ float dppq(float v) {
  return __int_as_float(__builtin_amdgcn_update_dpp(
      0, __float_as_int(v), CTRL, 0xF, 0xF, true));
}
__device__ __forceinline__ float qmax(float v) {
  v = fmaxf(v, dppq<0xB1>(v));
  v = fmaxf(v, dppq<0x4E>(v));
  return v;
}
__device__ __forceinline__ float qsum(float v) {
  v += dppq<0xB1>(v);
  v += dppq<0x4E>(v);
  return v;
}
// ds_swizzle BitMode xor exchange (within 32-lane halves; G<=32).
template <int MASK>
__device__ __forceinline__ float swz(float v) {
  return __int_as_float(__builtin_amdgcn_ds_swizzle(
      __float_as_int(v), (MASK << 10) | 0x1F));
}
template <int G>
__device__ __forceinline__ float gmaxr(float v) {
  v = qmax(v);
  if constexpr (G >= 8)  v = fmaxf(v, swz<4>(v));
  if constexpr (G >= 16) v = fmaxf(v, swz<8>(v));
  if constexpr (G >= 32) v = fmaxf(v, swz<16>(v));
  return v;
}
template <int G>
__device__ __forceinline__ float gsumr(float v) {
  v = qsum(v);
  if constexpr (G >= 8)  v += swz<4>(v);
  if constexpr (G >= 16) v += swz<8>(v);
  if constexpr (G >= 32) v += swz<16>(v);
  return v;
}

// ---------------- small-w path (w<=64): quad per i, register streams -------
// paR[k]=sc[ii][ii+j], a1R[k]=sc[ii+j][ii], c1R[k]=si[ii][ii+4k+jg+1];
// unfilled slot = -inf == exact validity mask (no +inf exists -> no NaN).
template <int K>
__device__ __forceinline__ void fusedPhase(
    float* __restrict__ tC, float* __restrict__ tI, const float* __restrict__ S,
    const int ii, const int w, const int jg, const bool writer,
    const bool rootBad, float (&paR)[17], float (&a1R)[17], float (&c1R)[17]) {
  const float sUp = S[ii * LL + ii + w];
  const float sLo = S[(ii + w) * LL + ii];
  const float* pb = tC + (ii + w) * LP + ii + 1 + jg;   // stride 16B
  const float* a2 = tI + (ii + w) * LP + ii + jg;       // stride 16B
  const float* c2 = tC + (ii + 1 + jg) * LP + ii + w;   // stride 4*LP

  float vb[K], va[K], vc[K];
#pragma unroll
  for (int k = 0; k < K; ++k) vb[k] = pb[4 * k];
#pragma unroll
  for (int k = 0; k < K; ++k) va[k] = a2[4 * k];
#pragma unroll
  for (int k = 0; k < K; ++k) vc[k] = c2[4 * k * LP];

  float mA0 = -INFINITY, mA1 = -INFINITY;
#pragma unroll
  for (int k = 0; k < K; ++k) {
    float x = paR[k] + vb[k];
    if (k & 1) mA1 = fmaxf(mA1, x); else mA0 = fmaxf(mA0, x);
  }
  const float msA = fmaxf(qmax(fmaxf(mA0, mA1)), -1e37f);
  const float nA = -msA * LOG2E;
  float sA0 = 0.f, sA1 = 0.f;
#pragma unroll
  for (int k = 0; k < K; ++k) {
    float e = __builtin_amdgcn_exp2f(__builtin_fmaf(paR[k] + vb[k], LOG2E, nA));
    if (k & 1) sA1 += e; else sA0 += e;
  }
  const float il = __builtin_amdgcn_logf(qsum(sA0 + sA1)) * LN2 + msA;

  float mL0 = -INFINITY, mL1 = -INFINITY;
#pragma unroll
  for (int k = 0; k < K; ++k) {
    float x = a1R[k] + va[k];
    if (k & 1) mL1 = fmaxf(mL1, x); else mL0 = fmaxf(mL0, x);
  }
  const float mL = qmax(fmaxf(mL0, mL1));
  const float msL = fmaxf(mL, -1e37f);
  const float nL = -msL * LOG2E;
  float sL0 = 0.f, sL1 = 0.f;
#pragma unroll
  for (int k = 0; k < K; ++k) {
    float e = __builtin_amdgcn_exp2f(__builtin_fmaf(a1R[k] + va[k], LOG2E, nL));
    if (k & 1) sL1 += e; else sL0 += e;
  }
  const float SL = qsum(sL0 + sL1);

  float mR0 = -INFINITY, mR1 = -INFINITY;
#pragma unroll
  for (int k = 0; k < K; ++k) {
    float x = c1R[k] + vc[k];
    if (k & 1) mR1 = fmaxf(mR1, x); else mR0 = fmaxf(mR0, x);
  }
  const float mR = qmax(fmaxf(mR0, mR1));
  const float msR = fmaxf(mR, -1e37f);
  const float nR = -msR * LOG2E;
  float sR0 = 0.f, sR1 = 0.f;
#pragma unroll
  for (int k = 0; k < K; ++k) {
    float e = __builtin_amdgcn_exp2f(__builtin_fmaf(c1R[k] + vc[k], LOG2E, nR));
    if (k & 1) sR1 += e; else sR0 += e;
  }
  const float SR = qsum(sR0 + sR1);

  const float t0 = il + sUp;
  const float tW = il + sLo;
  const float msfL = fmaxf(fmaxf(mL, t0), -1e37f);
  const float SLf = SL * __builtin_amdgcn_exp2f((msL - msfL) * LOG2E)
                  + __builtin_amdgcn_exp2f((t0 - msfL) * LOG2E);
  const float clv = __builtin_amdgcn_logf(SLf) * LN2 + msfL;
  const float msfR = fmaxf(fmaxf(mR, tW), -1e37f);
  const float SRf = SR * __builtin_amdgcn_exp2f((msR - msfR) * LOG2E)
                  + __builtin_amdgcn_exp2f((tW - msfR) * LOG2E);
  float crv = __builtin_amdgcn_logf(SRf) * LN2 + msfR;
  if (rootBad) crv = -INFINITY;

  if (writer) {
    tI[(ii + w) * LP + ii] = t0;
    tI[ii * LP + (ii + w)] = tW;
    tC[(ii + w) * LP + ii] = clv;
    tC[ii * LP + (ii + w)] = crv;
  }

  // register appends (static slots)
  const int wm3 = w & 3;
  const bool lnw = (jg == wm3) && (wm3 != 0);
  paR[K - 1] = lnw ? crv : paR[K - 1];
  a1R[K - 1] = lnw ? clv : a1R[K - 1];
  if constexpr (K < 16) {
    const bool z = (jg == 0) && (wm3 == 0);
    paR[K] = z ? crv : paR[K];
    a1R[K] = z ? clv : a1R[K];
  } else {
    const bool z = (jg == 0) && (wm3 == 0);
    paR[16] = z ? crv : paR[16];
    a1R[16] = z ? clv : a1R[16];
  }
  const bool ln1 = (jg == ((w - 1) & 3));
  c1R[K - 1] = ln1 ? tW : c1R[K - 1];
}

// ---------------- wide path (w>64): G lanes per i, all streams from LDS ----
template <int G, int KG>
__device__ __forceinline__ void widePhase(
    float* __restrict__ tC, float* __restrict__ tI, const float* __restrict__ S,
    const int ii, const int w, const int jgg, const bool writer,
    const bool rootBad) {
  const float sUp = S[ii * LL + ii + w];
  const float sLo = S[(ii + w) * LL + ii];
  const float* pa = tC + ii * LP + ii + jgg;
  const float* pb = tC + (ii + w) * LP + ii + 1 + jgg;
  const float* a1 = tC + (ii + jgg) * LP + ii;
  const float* a2 = tI + (ii + w) * LP + ii + jgg;
  const float* c1 = tI + ii * LP + ii + 1 + jgg;
  const float* c2 = tC + (ii + 1 + jgg) * LP + ii + w;

  float xa[KG], xl[KG], xr[KG];
  const unsigned uw = (unsigned)w, uw1 = (unsigned)(w - 1);
#pragma unroll
  for (int k = 0; k < KG; ++k) {
    float va_ = pa[G * k] + pb[G * k];
    float vl_ = a1[G * k * LP] + a2[G * k];
    float vr_ = c1[G * k] + c2[G * k * LP];
    const unsigned j = (unsigned)(jgg + G * k);
    xa[k] = (j < uw) ? va_ : -INFINITY;        // A: j in [0,w)
    xl[k] = (j - 1u < uw1) ? vl_ : -INFINITY;  // L bulk: j in [1,w)
    xr[k] = (j < uw1) ? vr_ : -INFINITY;       // R bulk: j in [0,w-1)
  }

  float mA0 = -INFINITY, mA1 = -INFINITY;
#pragma unroll
  for (int k = 0; k < KG; ++k) {
    if (k & 1) mA1 = fmaxf(mA1, xa[k]); else mA0 = fmaxf(mA0, xa[k]);
  }
  const float msA = fmaxf(gmaxr<G>(fmaxf(mA0, mA1)), -1e37f);
  const float nA = -msA * LOG2E;
  float sA0 = 0.f, sA1 = 0.f;
#pragma unroll
  for (int k = 0; k < KG; ++k) {
    float e = __builtin_amdgcn_exp2f(__builtin_fmaf(xa[k], LOG2E, nA));
    if (k & 1) sA1 += e; else sA0 += e;
  }
  const float il = __builtin_amdgcn_logf(gsumr<G>(sA0 + sA1)) * LN2 + msA;

  float mL0 = -INFINITY, mL1 = -INFINITY;
#pragma unroll
  for (int k = 0; k < KG; ++k) {
    if (k & 1) mL1 = fmaxf(mL1, xl[k]); else mL0 = fmaxf(mL0, xl[k]);
  }
  const float mL = gmaxr<G>(fmaxf(mL0, mL1));
  const float msL = fmaxf(mL, -1e37f);
  const float nL = -msL * LOG2E;
  float sL0 = 0.f, sL1 = 0.f;
#pragma unroll
  for (int k = 0; k < KG; ++k) {
    float e = __builtin_amdgcn_exp2f(__builtin_fmaf(xl[k], LOG2E, nL));
    if (k & 1) sL1 += e; else sL0 += e;
  }
  const float SL = gsumr<G>(sL0 + sL1);

  float mR0 = -INFINITY, mR1 = -INFINITY;
#pragma unroll
  for (int k = 0; k < KG; ++k) {
    if (k & 1) mR1 = fmaxf(mR1, xr[k]); else mR0 = fmaxf(mR0, xr[k]);
  }
  const float mR = gmaxr<G>(fmaxf(mR0, mR1));
  const float msR = fmaxf(mR, -1e37f);
  const float nR = -msR * LOG2E;
  float sR0 = 0.f, sR1 = 0.f;
#pragma unroll
  for (int k = 0; k < KG; ++k) {
    float e = __builtin_amdgcn_exp2f(__builtin_fmaf(xr[k], LOG2E, nR));
    if (k & 1) sR1 += e; else sR0 += e;
  }
  const float SR = gsumr<G>(sR0 + sR1);

  const float t0 = il + sUp;
  const float tW = il + sLo;
  const float msfL = fmaxf(fmaxf(mL, t0), -1e37f);
  const float SLf = SL * __builtin_amdgcn_exp2f((msL - msfL) * LOG2E)
                  + __builtin_amdgcn_exp2f((t0 - msfL) * LOG2E);
  const float clv = __builtin_amdgcn_logf(SLf) * LN2 + msfL;
  const float msfR = fmaxf(fmaxf(mR, tW), -1e37f);
  const float SRf = SR * __builtin_amdgcn_exp2f((msR - msfR) * LOG2E)
                  + __builtin_amdgcn_exp2f((tW - msfR) * LOG2E);
  float crv = __builtin_amdgcn_logf(SRf) * LN2 + msfR;
  if (rootBad) crv = -INFINITY;

  if (writer) {
    tI[(ii + w) * LP + ii] = t0;
    tI[ii * LP + (ii + w)] = tW;
    tC[(ii + w) * LP + ii] = clv;
    tC[ii * LP + (ii + w)] = crv;
  }
}

__global__ __launch_bounds__(NT, 2) void crf_inside(
    const float* __restrict__ scores, const int* __restrict__ mask,
    const int* __restrict__ target, float* __restrict__ acc) {
  extern __shared__ float lds[];
  float* tC = lds;          // complete spans (incl. guard rows)
  float* tI = lds + TC_SZ;  // incomplete spans
  const int b = blockIdx.x;
  const int t = threadIdx.x;
  const int lane = t & 63;
  const int wv = t >> 6;
  const int r = lane >> 2;
  const int jg = lane & 3;
  const float* S = scores + (size_t)b * LL * LL;

  __shared__ float gred[NW];
  __shared__ int lred[NW];
  __shared__ float s_gold;
  __shared__ int s_len;

  int mv = 0; float gv = 0.f;
  if (t < LL) {
    mv = mask[b * LL + t] ? 1 : 0;
    if (mv) gv = S[t * LL + target[b * LL + t]];
  }
  int lm = mv; float lg = gv;
#pragma unroll
  for (int o = 32; o > 0; o >>= 1) {
    lm += __shfl_xor(lm, o, 64);
    lg += __shfl_xor(lg, o, 64);
  }
  if (lane == 0) { lred[wv] = lm; gred[wv] = lg; }

  for (int idx = t; idx < TC_SZ + TI_SZ; idx += NT) lds[idx] = -INFINITY;
  __syncthreads();
  if (t < LL) tC[t * LP + t] = 0.f;
  if (t == 0) {
    int l = 0; float g = 0.f;
    for (int k = 0; k < NW; ++k) { l += lred[k]; g += gred[k]; }
    s_len = l; s_gold = g;
  }
  __syncthreads();
  const int len = s_len;

  const int i = (wv << 4) + r;

  float paR[17], a1R[17], c1R[17];
#pragma unroll
  for (int k = 0; k < 17; ++k) { paR[k] = -INFINITY; a1R[k] = -INFINITY; c1R[k] = -INFINITY; }
  if (jg == 0) paR[0] = 0.f;

  // ---- w = 1..64: quad per i with register streams ----
  for (int w = 1; w <= 64; ++w) {
    const int ni = LL - w;
    const bool waveAct = (wv << 4) < ni;
    const int ii = min(i, ni - 1);
    const bool writer = (jg == 0) & (i < ni);
    const bool rootBad = (ii == 0) && (w != len);
    const int K = (w + 3) >> 2;
    if (waveAct) {
      switch (K) {
#define CASE_K(KK) case KK: fusedPhase<KK>(tC, tI, S, ii, w, jg, writer, rootBad, paR, a1R, c1R); break;
        CASE_K(1) CASE_K(2) CASE_K(3) CASE_K(4) CASE_K(5) CASE_K(6)
        CASE_K(7) CASE_K(8) CASE_K(9) CASE_K(10) CASE_K(11) CASE_K(12)
        CASE_K(13) CASE_K(14) CASE_K(15) CASE_K(16)
#undef CASE_K
      }
    }
    __syncthreads();
  }

  // ---- w = 65..127: G lanes per i (G grows as ni shrinks) ----
  for (int w = 65; w < LL; ++w) {
    const int ni = LL - w;
    if (w <= 96) {             // G=8, 64 groups
      const int gi = t >> 3, jgg = t & 7;
      if ((wv << 3) < ni) {
        const int ii = min(gi, ni - 1);
        const bool writer = (jgg == 0) & (gi < ni);
        const bool rootBad = (ii == 0) && (w != len);
        switch ((w + 7) >> 3) {
          case 9:  widePhase<8, 9>(tC, tI, S, ii, w, jgg, writer, rootBad); break;
          case 10: widePhase<8, 10>(tC, tI, S, ii, w, jgg, writer, rootBad); break;
          case 11: widePhase<8, 11>(tC, tI, S, ii, w, jgg, writer, rootBad); break;
          default: widePhase<8, 12>(tC, tI, S, ii, w, jgg, writer, rootBad); break;
        }
      }
    } else if (w <= 112) {     // G=16, 32 groups; ceil(w/16)=7 throughout
      const int gi = t >> 4, jgg = t & 15;
      if ((wv << 2) < ni) {
        const int ii = min(gi, ni - 1);
        const bool writer = (jgg == 0) & (gi < ni);
        const bool rootBad = (ii == 0) && (w != len);
        widePhase<16, 7>(tC, tI, S, ii, w, jgg, writer, rootBad);
      }
    } else {                   // G=32, 16 groups; ceil(w/32)=4 throughout
      const int gi = t >> 5, jgg = t & 31;
      if ((wv << 1) < ni) {
        const int ii = min(gi, ni - 1);
        const bool writer = (jgg == 0) & (gi < ni);
        const bool rootBad = (ii == 0) && (w != len);
        widePhase<32, 4>(tC, tI, S, ii, w, jgg, writer, rootBad);
      }
    }
    __syncthreads();
  }

  if (t == 0) {
    float logZ = tC[len];  // sc[0][len]
    atomicAdd(&acc[0], logZ - s_gold);
    atomicAdd(&acc[1], (float)len);
  }
}

__global__ void zero_acc(float* acc) {
  acc[0] = 0.f;
  acc[1] = 0.f;
}

__global__ void finalize(const float* __restrict__ acc, float* __restrict__ out) {
  out[0] = acc[0] / acc[1];
}

extern "C" void kernel_launch(void* const* d_in, const int* in_sizes, int n_in,
                              void* d_out, int out_size, void* d_ws, size_t ws_size,
                              hipStream_t stream) {
  const float* scores = (const float*)d_in[0];
  const int* mask = (const int*)d_in[1];
  const int* target = (const int*)d_in[2];
  float* out = (float*)d_out;
  float* acc = (float*)d_ws;

  const int Bn = in_sizes[0] / (LL * LL);
  const size_t lds_bytes = (size_t)(TC_SZ + TI_SZ) * sizeof(float);  // 140992 B

  (void)hipFuncSetAttribute((const void*)crf_inside,
                            hipFuncAttributeMaxDynamicSharedMemorySize,
                            (int)lds_bytes);

  zero_acc<<<1, 1, 0, stream>>>(acc);
  crf_inside<<<Bn, NT, lds_bytes, stream>>>(scores, mask, target, acc);
  finalize<<<1, 1, 0, stream>>>(acc, out);
}

// Round 11
// 251.054 us; speedup vs baseline: 1.0660x; 1.0660x over previous
//
#include <hip/hip_runtime.h>
#include <math.h>

#define LL 128                  // sequence length
#define LP 129                  // padded row stride (floats)
#define TCR 136                 // tC rows incl. guard (c2 rows reach 135)
#define TC_SZ (TCR * LP)        // 17544 floats
#define TI_SZ (LL * LP + 40)    // 16552 floats (col-overshoot reads reach 16517)
#define NT 1024
#define NW 16

#define LOG2E 1.4426950408889634f
#define LN2   0.6931471805599453f

// DPP cross-lane reductions, all VALU (no LDS pipe).
// 0xB1 = quad_perm[1,0,3,2] (xor1), 0x4E = quad_perm[2,3,0,1] (xor2),
// 0x141 = row_half_mirror (xor7 within 8 lanes; quad-uniform input => xor4).
template <int CTRL>
__device__ __forceinline__ float dppq(float v) {
  return __int_as_float(__builtin_amdgcn_update_dpp(
      0, __float_as_int(v), CTRL, 0xF, 0xF, true));
}
__device__ __forceinline__ float g8max(float v) {
  v = fmaxf(v, dppq<0xB1>(v));
  v = fmaxf(v, dppq<0x4E>(v));
  v = fmaxf(v, dppq<0x141>(v));
  return v;
}
__device__ __forceinline__ float g8sum(float v) {
  v += dppq<0xB1>(v);
  v += dppq<0x4E>(v);
  v += dppq<0x141>(v);
  return v;
}

// Fused A+B phase, width w, K = ceil(w/8) (compile-time). 8-lane group per
// span-start i; lane lg owns j = 8k+lg. Register-resident streams (filled
// exactly when the entry becomes valid; unfilled = -inf = exact validity
// mask, and no +inf exists so no NaN):
//   paR[k] = sc[ii][ii+8k+lg]   (appended at w'=j: crv; lane0/slot0 = diag 0)
//   a1R[k] = sc[ii+8k+lg][ii]   (appended at w'=j: clv)
//   c1R[k] = si[ii][ii+8k+lg+1] (appended at w'=8k+lg+1: tW)
// LDS streams (old data only): pb, a2, c2. B's width-w terms (j=0 of cl,
// j=w-1 of cr) are group-local register-forwarded (t0/tW) via lse fix-up,
// so one barrier per width suffices.
template <int K>
__device__ __forceinline__ void fusedPhase(
    float* __restrict__ tC, float* __restrict__ tI, const float* __restrict__ S,
    const int ii, const int w, const int lg, const bool writer,
    const bool rootBad, float (&paR)[17], float (&a1R)[17], float (&c1R)[16]) {
  const float sUp = S[ii * LL + ii + w];        // global (L2) loads first
  const float sLo = S[(ii + w) * LL + ii];
  const float* pb = tC + (ii + w) * LP + ii + 1 + lg;   // [8k]
  const float* a2 = tI + (ii + w) * LP + ii + lg;       // [8k]
  const float* c2 = tC + (ii + 1 + lg) * LP + ii + w;   // [8k*LP]

  // ---- window 1: A + L streams ----
  float vb[K], va[K];
#pragma unroll
  for (int k = 0; k < K; ++k) vb[k] = pb[8 * k];
#pragma unroll
  for (int k = 0; k < K; ++k) va[k] = a2[8 * k];

  // A: il = lse_j[ sc[ii][ii+j] + sc[ii+w][ii+j+1] ]
  float mA0 = -INFINITY, mA1 = -INFINITY;
#pragma unroll
  for (int k = 0; k < K; ++k) {
    float x = paR[k] + vb[k];
    if (k & 1) mA1 = fmaxf(mA1, x); else mA0 = fmaxf(mA0, x);
  }
  const float msA = fmaxf(g8max(fmaxf(mA0, mA1)), -1e37f);
  const float nA = -msA * LOG2E;
  float sA0 = 0.f, sA1 = 0.f;
#pragma unroll
  for (int k = 0; k < K; ++k) {
    float e = __builtin_amdgcn_exp2f(__builtin_fmaf(paR[k] + vb[k], LOG2E, nA));
    if (k & 1) sA1 += e; else sA0 += e;
  }
  const float il = __builtin_amdgcn_logf(g8sum(sA0 + sA1)) * LN2 + msA;

  // L bulk: lse_j[ sc[ii+j][ii] + si[ii+w][ii+j] ], j in [1,w)
  float mL0 = -INFINITY, mL1 = -INFINITY;
#pragma unroll
  for (int k = 0; k < K; ++k) {
    float x = a1R[k] + va[k];
    if (k & 1) mL1 = fmaxf(mL1, x); else mL0 = fmaxf(mL0, x);
  }
  const float mL = g8max(fmaxf(mL0, mL1));
  const float msL = fmaxf(mL, -1e37f);
  const float nL = -msL * LOG2E;
  float sL0 = 0.f, sL1 = 0.f;
#pragma unroll
  for (int k = 0; k < K; ++k) {
    float e = __builtin_amdgcn_exp2f(__builtin_fmaf(a1R[k] + va[k], LOG2E, nL));
    if (k & 1) sL1 += e; else sL0 += e;
  }
  const float SL = g8sum(sL0 + sL1);

  // ---- window 2: R stream ----
  float vc[K];
#pragma unroll
  for (int k = 0; k < K; ++k) vc[k] = c2[8 * k * LP];

  // R bulk: lse_d[ si[ii][ii+d] + sc[ii+d][ii+w] ], d in [1,w-1]
  float mR0 = -INFINITY, mR1 = -INFINITY;
#pragma unroll
  for (int k = 0; k < K; ++k) {
    float x = c1R[k] + vc[k];
    if (k & 1) mR1 = fmaxf(mR1, x); else mR0 = fmaxf(mR0, x);
  }
  const float mR = g8max(fmaxf(mR0, mR1));
  const float msR = fmaxf(mR, -1e37f);
  const float nR = -msR * LOG2E;
  float sR0 = 0.f, sR1 = 0.f;
#pragma unroll
  for (int k = 0; k < K; ++k) {
    float e = __builtin_amdgcn_exp2f(__builtin_fmaf(c1R[k] + vc[k], LOG2E, nR));
    if (k & 1) sR1 += e; else sR0 += e;
  }
  const float SR = g8sum(sR0 + sR1);

  // ---- fix-up with group-local width-w terms ----
  const float t0 = il + sUp;   // cl j=0   : sc[ii][ii]=0 + si[ii+w][ii]
  const float tW = il + sLo;   // cr d=w   : si[ii][ii+w] + sc[ii+w][ii+w]=0
  const float msfL = fmaxf(fmaxf(mL, t0), -1e37f);
  const float SLf = SL * __builtin_amdgcn_exp2f((msL - msfL) * LOG2E)
                  + __builtin_amdgcn_exp2f((t0 - msfL) * LOG2E);
  const float clv = __builtin_amdgcn_logf(SLf) * LN2 + msfL;
  const float msfR = fmaxf(fmaxf(mR, tW), -1e37f);
  const float SRf = SR * __builtin_amdgcn_exp2f((msR - msfR) * LOG2E)
                  + __builtin_amdgcn_exp2f((tW - msfR) * LOG2E);
  float crv = __builtin_amdgcn_logf(SRf) * LN2 + msfR;
  if (rootBad) crv = -INFINITY;   // root-arity constraint

  // ---- stores (barrier placed by caller) ----
  if (writer) {
    tI[(ii + w) * LP + ii] = t0;
    tI[ii * LP + (ii + w)] = tW;
    tC[(ii + w) * LP + ii] = clv;
    tC[ii * LP + (ii + w)] = crv;
  }

  // ---- register appends (static slots; masked lane-select) ----
  // paR/a1R: new j=w -> slot w>>3 = K-1 (w&7!=0, lane w&7) or K (w&7==0, lane 0)
  const int wm7 = w & 7;
  const bool lnw = (lg == wm7) && (wm7 != 0);
  paR[K - 1] = lnw ? crv : paR[K - 1];
  a1R[K - 1] = lnw ? clv : a1R[K - 1];
  if constexpr (K < 16) {
    const bool z = (lg == 0) && (wm7 == 0);
    paR[K] = z ? crv : paR[K];
    a1R[K] = z ? clv : a1R[K];
  }
  // c1R: new d=w -> slot (w-1)>>3 = K-1, lane (w-1)&7
  const bool ln1 = (lg == ((w - 1) & 7));
  c1R[K - 1] = ln1 ? tW : c1R[K - 1];
}

__global__ __launch_bounds__(NT, 4) void crf_inside(
    const float* __restrict__ scores, const int* __restrict__ mask,
    const int* __restrict__ target, float* __restrict__ acc) {
  extern __shared__ float lds[];
  float* tC = lds;          // complete spans (136 rows incl. guard)
  float* tI = lds + TC_SZ;  // incomplete spans
  const int b = blockIdx.x;
  const int t = threadIdx.x;
  const int lane = t & 63;
  const int wv = t >> 6;
  const int g = t >> 3;     // group index (0..127), 8 groups per wave
  const int lg = t & 7;     // lane in group
  const float* S = scores + (size_t)b * LL * LL;

  __shared__ float gred[NW];
  __shared__ int lred[NW];
  __shared__ float s_gold;
  __shared__ int s_len;

  // ---- lens + masked gold-score reduction (threads 0..127 hold data) ----
  int mv = 0; float gv = 0.f;
  if (t < LL) {
    mv = mask[b * LL + t] ? 1 : 0;
    if (mv) gv = S[t * LL + target[b * LL + t]];
  }
  int lm = mv; float lg_ = gv;
#pragma unroll
  for (int o = 32; o > 0; o >>= 1) {
    lm += __shfl_xor(lm, o, 64);
    lg_ += __shfl_xor(lg_, o, 64);
  }
  if (lane == 0) { lred[wv] = lm; gred[wv] = lg_; }

  // ---- init LDS (incl. guards) to -inf; diag of s_c = 0 ----
  for (int idx = t; idx < TC_SZ + TI_SZ; idx += NT) lds[idx] = -INFINITY;
  __syncthreads();
  if (t < LL) tC[t * LP + t] = 0.f;
  if (t == 0) {
    int l = 0; float gg = 0.f;
    for (int k = 0; k < NW; ++k) { l += lred[k]; gg += gred[k]; }
    s_len = l; s_gold = gg;
  }
  __syncthreads();
  const int len = s_len;

  // ---- register streams: -inf except paR[0] = diag 0 on lg==0 ----
  float paR[17], a1R[17], c1R[16];
#pragma unroll
  for (int k = 0; k < 17; ++k) { paR[k] = -INFINITY; a1R[k] = -INFINITY; }
#pragma unroll
  for (int k = 0; k < 16; ++k) c1R[k] = -INFINITY;
  if (lg == 0) paR[0] = 0.f;

  // ---- inside DP: one fused phase + one barrier per width ----
  for (int w = 1; w < LL; ++w) {
    const int ni = LL - w;
    const bool waveAct = (wv << 3) < ni;   // wave-uniform skip
    const int ii = min(g, ni - 1);         // clamped groups compute, no write
    const bool writer = (lg == 0) & (g < ni);
    const bool rootBad = (ii == 0) && (w != len);
    const int K = (w + 7) >> 3;
    if (waveAct) {
      switch (K) {
#define CASE_K(KK) case KK: fusedPhase<KK>(tC, tI, S, ii, w, lg, writer, rootBad, paR, a1R, c1R); break;
        CASE_K(1) CASE_K(2) CASE_K(3) CASE_K(4) CASE_K(5) CASE_K(6)
        CASE_K(7) CASE_K(8) CASE_K(9) CASE_K(10) CASE_K(11) CASE_K(12)
        CASE_K(13) CASE_K(14) CASE_K(15) CASE_K(16)
#undef CASE_K
      }
    }
    __syncthreads();
  }

  // ---- per-batch contribution ----
  if (t == 0) {
    float logZ = tC[len];  // sc[0][len]
    atomicAdd(&acc[0], logZ - s_gold);
    atomicAdd(&acc[1], (float)len);
  }
}

__global__ void zero_acc(float* acc) {
  acc[0] = 0.f;
  acc[1] = 0.f;
}

__global__ void finalize(const float* __restrict__ acc, float* __restrict__ out) {
  out[0] = acc[0] / acc[1];
}

extern "C" void kernel_launch(void* const* d_in, const int* in_sizes, int n_in,
                              void* d_out, int out_size, void* d_ws, size_t ws_size,
                              hipStream_t stream) {
  const float* scores = (const float*)d_in[0];
  const int* mask = (const int*)d_in[1];
  const int* target = (const int*)d_in[2];
  float* out = (float*)d_out;
  float* acc = (float*)d_ws;

  const int Bn = in_sizes[0] / (LL * LL);
  const size_t lds_bytes = (size_t)(TC_SZ + TI_SZ) * sizeof(float);  // 136384 B

  (void)hipFuncSetAttribute((const void*)crf_inside,
                            hipFuncAttributeMaxDynamicSharedMemorySize,
                            (int)lds_bytes);

  zero_acc<<<1, 1, 0, stream>>>(acc);
  crf_inside<<<Bn, NT, lds_bytes, stream>>>(scores, mask, target, acc);
  finalize<<<1, 1, 0, stream>>>(acc, out);
}

// Round 12
// 243.102 us; speedup vs baseline: 1.1009x; 1.0327x over previous
//
#include <hip/hip_runtime.h>
#include <math.h>

#define LL 128                  // sequence length
#define LP 132                  // padded row stride: base stride 133==5 (mod 32)
                                // -> 8-lane group windows tile banks <=2-way
#define TCR 136                 // tC rows incl. guard (reads reach row 134)
#define TC_SZ (TCR * LP)        // 17952 floats
#define TI_SZ (LL * LP + 48)    // 16944 floats (col-overshoot reads reach 16897)
#define NT 1024
#define NW 16

#define LOG2E 1.4426950408889634f
#define LN2   0.6931471805599453f

// DPP cross-lane reductions, all VALU (no LDS pipe).
// 0xB1 = quad_perm[1,0,3,2] (xor1), 0x4E = quad_perm[2,3,0,1] (xor2),
// 0x141 = row_half_mirror (xor7 within 8 lanes; quad-uniform input => xor4).
template <int CTRL>
__device__ __forceinline__ float dppq(float v) {
  return __int_as_float(__builtin_amdgcn_update_dpp(
      0, __float_as_int(v), CTRL, 0xF, 0xF, true));
}
__device__ __forceinline__ float g8max(float v) {
  v = fmaxf(v, dppq<0xB1>(v));
  v = fmaxf(v, dppq<0x4E>(v));
  v = fmaxf(v, dppq<0x141>(v));
  return v;
}
__device__ __forceinline__ float g8sum(float v) {
  v += dppq<0xB1>(v);
  v += dppq<0x4E>(v);
  v += dppq<0x141>(v);
  return v;
}

// Fused A+B phase, width w, K = ceil(w/8) (compile-time). 8-lane group per
// span-start i; lane lg owns j = 8k+lg. Register-resident streams (filled
// exactly when the entry becomes valid; unfilled = -inf = exact validity
// mask, and no +inf exists so no NaN):
//   paR[k] = sc[ii][ii+8k+lg]   (appended at w'=j: crv; lane0/slot0 = diag 0)
//   a1R[k] = sc[ii+8k+lg][ii]   (appended at w'=j: clv)
//   c1R[k] = si[ii][ii+8k+lg+1] (appended at w'=8k+lg+1: tW)
// LDS streams (old data only): pb, a2, c2 — all issued in ONE batch, fenced
// by sched_barrier(0) so the compiler cannot re-roll them into the use chain.
template <int K>
__device__ __forceinline__ void fusedPhase(
    float* __restrict__ tC, float* __restrict__ tI, const float* __restrict__ S,
    const int ii, const int w, const int lg, const bool writer,
    const bool rootBad, float (&paR)[17], float (&a1R)[17], float (&c1R)[16]) {
  const float sUp = S[ii * LL + ii + w];        // global (L2) loads first
  const float sLo = S[(ii + w) * LL + ii];
  const float* pb = tC + (ii + w) * LP + ii + 1 + lg;   // [8k]
  const float* a2 = tI + (ii + w) * LP + ii + lg;       // [8k]
  const float* c2 = tC + (ii + 1 + lg) * LP + ii + w;   // [8k*LP]

  // ---- single load window: all 3K ds_reads issue back-to-back ----
  float vb[K], va[K], vc[K];
#pragma unroll
  for (int k = 0; k < K; ++k) vb[k] = pb[8 * k];
#pragma unroll
  for (int k = 0; k < K; ++k) va[k] = a2[8 * k];
#pragma unroll
  for (int k = 0; k < K; ++k) vc[k] = c2[8 * k * LP];
  __builtin_amdgcn_sched_barrier(0);   // fence: loads stay batched above uses

  // A: il = lse_j[ sc[ii][ii+j] + sc[ii+w][ii+j+1] ]
  float mA0 = -INFINITY, mA1 = -INFINITY;
#pragma unroll
  for (int k = 0; k < K; ++k) {
    float x = paR[k] + vb[k];
    if (k & 1) mA1 = fmaxf(mA1, x); else mA0 = fmaxf(mA0, x);
  }
  const float msA = fmaxf(g8max(fmaxf(mA0, mA1)), -1e37f);
  const float nA = -msA * LOG2E;
  float sA0 = 0.f, sA1 = 0.f;
#pragma unroll
  for (int k = 0; k < K; ++k) {
    float e = __builtin_amdgcn_exp2f(__builtin_fmaf(paR[k] + vb[k], LOG2E, nA));
    if (k & 1) sA1 += e; else sA0 += e;
  }
  const float il = __builtin_amdgcn_logf(g8sum(sA0 + sA1)) * LN2 + msA;

  // L bulk: lse_j[ sc[ii+j][ii] + si[ii+w][ii+j] ], j in [1,w)
  float mL0 = -INFINITY, mL1 = -INFINITY;
#pragma unroll
  for (int k = 0; k < K; ++k) {
    float x = a1R[k] + va[k];
    if (k & 1) mL1 = fmaxf(mL1, x); else mL0 = fmaxf(mL0, x);
  }
  const float mL = g8max(fmaxf(mL0, mL1));
  const float msL = fmaxf(mL, -1e37f);
  const float nL = -msL * LOG2E;
  float sL0 = 0.f, sL1 = 0.f;
#pragma unroll
  for (int k = 0; k < K; ++k) {
    float e = __builtin_amdgcn_exp2f(__builtin_fmaf(a1R[k] + va[k], LOG2E, nL));
    if (k & 1) sL1 += e; else sL0 += e;
  }
  const float SL = g8sum(sL0 + sL1);

  // R bulk: lse_d[ si[ii][ii+d] + sc[ii+d][ii+w] ], d in [1,w-1]
  float mR0 = -INFINITY, mR1 = -INFINITY;
#pragma unroll
  for (int k = 0; k < K; ++k) {
    float x = c1R[k] + vc[k];
    if (k & 1) mR1 = fmaxf(mR1, x); else mR0 = fmaxf(mR0, x);
  }
  const float mR = g8max(fmaxf(mR0, mR1));
  const float msR = fmaxf(mR, -1e37f);
  const float nR = -msR * LOG2E;
  float sR0 = 0.f, sR1 = 0.f;
#pragma unroll
  for (int k = 0; k < K; ++k) {
    float e = __builtin_amdgcn_exp2f(__builtin_fmaf(c1R[k] + vc[k], LOG2E, nR));
    if (k & 1) sR1 += e; else sR0 += e;
  }
  const float SR = g8sum(sR0 + sR1);

  // ---- fix-up with group-local width-w terms ----
  const float t0 = il + sUp;   // cl j=0   : sc[ii][ii]=0 + si[ii+w][ii]
  const float tW = il + sLo;   // cr d=w   : si[ii][ii+w] + sc[ii+w][ii+w]=0
  const float msfL = fmaxf(fmaxf(mL, t0), -1e37f);
  const float SLf = SL * __builtin_amdgcn_exp2f((msL - msfL) * LOG2E)
                  + __builtin_amdgcn_exp2f((t0 - msfL) * LOG2E);
  const float clv = __builtin_amdgcn_logf(SLf) * LN2 + msfL;
  const float msfR = fmaxf(fmaxf(mR, tW), -1e37f);
  const float SRf = SR * __builtin_amdgcn_exp2f((msR - msfR) * LOG2E)
                  + __builtin_amdgcn_exp2f((tW - msfR) * LOG2E);
  float crv = __builtin_amdgcn_logf(SRf) * LN2 + msfR;
  if (rootBad) crv = -INFINITY;   // root-arity constraint

  // ---- stores (barrier placed by caller) ----
  if (writer) {
    tI[(ii + w) * LP + ii] = t0;
    tI[ii * LP + (ii + w)] = tW;
    tC[(ii + w) * LP + ii] = clv;
    tC[ii * LP + (ii + w)] = crv;
  }

  // ---- register appends (static slots; masked lane-select) ----
  // paR/a1R: new j=w -> slot w>>3 = K-1 (w&7!=0, lane w&7) or K (w&7==0, lane 0)
  const int wm7 = w & 7;
  const bool lnw = (lg == wm7) && (wm7 != 0);
  paR[K - 1] = lnw ? crv : paR[K - 1];
  a1R[K - 1] = lnw ? clv : a1R[K - 1];
  if constexpr (K < 16) {
    const bool z = (lg == 0) && (wm7 == 0);
    paR[K] = z ? crv : paR[K];
    a1R[K] = z ? clv : a1R[K];
  }
  // c1R: new d=w -> slot (w-1)>>3 = K-1, lane (w-1)&7
  const bool ln1 = (lg == ((w - 1) & 7));
  c1R[K - 1] = ln1 ? tW : c1R[K - 1];
}

__global__ __launch_bounds__(NT, 4) void crf_inside(
    const float* __restrict__ scores, const int* __restrict__ mask,
    const int* __restrict__ target, float* __restrict__ acc) {
  extern __shared__ float lds[];
  float* tC = lds;          // complete spans (136 rows incl. guard)
  float* tI = lds + TC_SZ;  // incomplete spans
  const int b = blockIdx.x;
  const int t = threadIdx.x;
  const int lane = t & 63;
  const int wv = t >> 6;
  const int g = t >> 3;     // group index (0..127), 8 groups per wave
  const int lg = t & 7;     // lane in group
  const float* S = scores + (size_t)b * LL * LL;

  __shared__ float gred[NW];
  __shared__ int lred[NW];
  __shared__ float s_gold;
  __shared__ int s_len;

  // ---- lens + masked gold-score reduction (threads 0..127 hold data) ----
  int mv = 0; float gv = 0.f;
  if (t < LL) {
    mv = mask[b * LL + t] ? 1 : 0;
    if (mv) gv = S[t * LL + target[b * LL + t]];
  }
  int lm = mv; float lg_ = gv;
#pragma unroll
  for (int o = 32; o > 0; o >>= 1) {
    lm += __shfl_xor(lm, o, 64);
    lg_ += __shfl_xor(lg_, o, 64);
  }
  if (lane == 0) { lred[wv] = lm; gred[wv] = lg_; }

  // ---- init LDS (incl. guards) to -inf; diag of s_c = 0 ----
  for (int idx = t; idx < TC_SZ + TI_SZ; idx += NT) lds[idx] = -INFINITY;
  __syncthreads();
  if (t < LL) tC[t * LP + t] = 0.f;
  if (t == 0) {
    int l = 0; float gg = 0.f;
    for (int k = 0; k < NW; ++k) { l += lred[k]; gg += gred[k]; }
    s_len = l; s_gold = gg;
  }
  __syncthreads();
  const int len = s_len;

  // ---- register streams: -inf except paR[0] = diag 0 on lg==0 ----
  float paR[17], a1R[17], c1R[16];
#pragma unroll
  for (int k = 0; k < 17; ++k) { paR[k] = -INFINITY; a1R[k] = -INFINITY; }
#pragma unroll
  for (int k = 0; k < 16; ++k) c1R[k] = -INFINITY;
  if (lg == 0) paR[0] = 0.f;

  // ---- inside DP: one fused phase + one barrier per width ----
  for (int w = 1; w < LL; ++w) {
    const int ni = LL - w;
    const bool waveAct = (wv << 3) < ni;   // wave-uniform skip
    const int ii = min(g, ni - 1);         // clamped groups compute, no write
    const bool writer = (lg == 0) & (g < ni);
    const bool rootBad = (ii == 0) && (w != len);
    const int K = (w + 7) >> 3;
    if (waveAct) {
      switch (K) {
#define CASE_K(KK) case KK: fusedPhase<KK>(tC, tI, S, ii, w, lg, writer, rootBad, paR, a1R, c1R); break;
        CASE_K(1) CASE_K(2) CASE_K(3) CASE_K(4) CASE_K(5) CASE_K(6)
        CASE_K(7) CASE_K(8) CASE_K(9) CASE_K(10) CASE_K(11) CASE_K(12)
        CASE_K(13) CASE_K(14) CASE_K(15) CASE_K(16)
#undef CASE_K
      }
    }
    __syncthreads();
  }

  // ---- per-batch contribution ----
  if (t == 0) {
    float logZ = tC[len];  // sc[0][len]
    atomicAdd(&acc[0], logZ - s_gold);
    atomicAdd(&acc[1], (float)len);
  }
}

__global__ void zero_acc(float* acc) {
  acc[0] = 0.f;
  acc[1] = 0.f;
}

__global__ void finalize(const float* __restrict__ acc, float* __restrict__ out) {
  out[0] = acc[0] / acc[1];
}

extern "C" void kernel_launch(void* const* d_in, const int* in_sizes, int n_in,
                              void* d_out, int out_size, void* d_ws, size_t ws_size,
                              hipStream_t stream) {
  const float* scores = (const float*)d_in[0];
  const int* mask = (const int*)d_in[1];
  const int* target = (const int*)d_in[2];
  float* out = (float*)d_out;
  float* acc = (float*)d_ws;

  const int Bn = in_sizes[0] / (LL * LL);
  const size_t lds_bytes = (size_t)(TC_SZ + TI_SZ) * sizeof(float);  // 139584 B

  (void)hipFuncSetAttribute((const void*)crf_inside,
                            hipFuncAttributeMaxDynamicSharedMemorySize,
                            (int)lds_bytes);

  zero_acc<<<1, 1, 0, stream>>>(acc);
  crf_inside<<<Bn, NT, lds_bytes, stream>>>(scores, mask, target, acc);
  finalize<<<1, 1, 0, stream>>>(acc, out);
}

// Round 13
// 237.424 us; speedup vs baseline: 1.1272x; 1.0239x over previous
//
#include <hip/hip_runtime.h>
#include <math.h>

#define LL 128                  // sequence length
#define LP 132                  // padded row stride: base stride 133==5 (mod 32)
                                // -> 8-lane group windows tile banks <=2-way
#define TCR 136                 // tC rows incl. guard (reads reach row 134)
#define TC_SZ (TCR * LP)        // 17952 floats
#define TI_SZ (LL * LP + 48)    // 16944 floats (col-overshoot reads reach 16897)
#define NT 1024
#define NW 16

#define LOG2E 1.4426950408889634f
#define LN2   0.6931471805599453f

// DPP cross-lane reductions, all VALU (no LDS pipe).
// 0xB1 = quad_perm[1,0,3,2] (xor1), 0x4E = quad_perm[2,3,0,1] (xor2),
// 0x141 = row_half_mirror (xor7 within 8 lanes; quad-uniform input => xor4).
template <int CTRL>
__device__ __forceinline__ float dppq(float v) {
  return __int_as_float(__builtin_amdgcn_update_dpp(
      0, __float_as_int(v), CTRL, 0xF, 0xF, true));
}
__device__ __forceinline__ float g8max(float v) {
  v = fmaxf(v, dppq<0xB1>(v));
  v = fmaxf(v, dppq<0x4E>(v));
  v = fmaxf(v, dppq<0x141>(v));
  return v;
}
__device__ __forceinline__ float g8sum(float v) {
  v += dppq<0xB1>(v);
  v += dppq<0x4E>(v);
  v += dppq<0x141>(v);
  return v;
}

// Fused A+B phase, width w, K = ceil(w/8) (compile-time). 8-lane group per
// span-start i; lane lg owns j = 8k+lg. Register-resident streams (filled
// exactly when the entry becomes valid; unfilled = -inf = exact validity
// mask, and no +inf exists so no NaN):
//   paR[k] = sc[ii][ii+8k+lg]   (appended at w'=j: crv; lane0/slot0 = diag 0)
//   a1R[k] = sc[ii+8k+lg][ii]   (appended at w'=j: clv)
//   c1R[k] = si[ii][ii+8k+lg+1] (appended at w'=8k+lg+1: tW)
// LDS streams (old data only): pb, a2, c2 — batched in two windows, each
// fenced by sched_barrier(0); amdgpu_waves_per_eu(4,4) unlocks the VGPR
// budget (occupancy is LDS-bound at 4 waves/EU anyway) so the batches
// survive register allocation instead of re-rolling into serial chains.
template <int K>
__device__ __forceinline__ void fusedPhase(
    float* __restrict__ tC, float* __restrict__ tI, const float* __restrict__ S,
    const int ii, const int w, const int lg, const bool writer,
    const bool rootBad, float (&paR)[17], float (&a1R)[17], float (&c1R)[16]) {
  const float sUp = S[ii * LL + ii + w];        // global (L2) loads first
  const float sLo = S[(ii + w) * LL + ii];
  const float* pb = tC + (ii + w) * LP + ii + 1 + lg;   // [8k]
  const float* a2 = tI + (ii + w) * LP + ii + lg;       // [8k]
  const float* c2 = tC + (ii + 1 + lg) * LP + ii + w;   // [8k*LP]

  // ---- load window 1: A + L streams (<=32 live) ----
  float vb[K], va[K];
#pragma unroll
  for (int k = 0; k < K; ++k) vb[k] = pb[8 * k];
#pragma unroll
  for (int k = 0; k < K; ++k) va[k] = a2[8 * k];
  __builtin_amdgcn_sched_barrier(0);   // loads stay batched above uses

  // A: il = lse_j[ sc[ii][ii+j] + sc[ii+w][ii+j+1] ]
  float mA0 = -INFINITY, mA1 = -INFINITY;
#pragma unroll
  for (int k = 0; k < K; ++k) {
    float x = paR[k] + vb[k];
    if (k & 1) mA1 = fmaxf(mA1, x); else mA0 = fmaxf(mA0, x);
  }
  const float msA = fmaxf(g8max(fmaxf(mA0, mA1)), -1e37f);
  const float nA = -msA * LOG2E;
  float sA0 = 0.f, sA1 = 0.f;
#pragma unroll
  for (int k = 0; k < K; ++k) {
    float e = __builtin_amdgcn_exp2f(__builtin_fmaf(paR[k] + vb[k], LOG2E, nA));
    if (k & 1) sA1 += e; else sA0 += e;
  }
  const float il = __builtin_amdgcn_logf(g8sum(sA0 + sA1)) * LN2 + msA;

  // L bulk: lse_j[ sc[ii+j][ii] + si[ii+w][ii+j] ], j in [1,w)
  float mL0 = -INFINITY, mL1 = -INFINITY;
#pragma unroll
  for (int k = 0; k < K; ++k) {
    float x = a1R[k] + va[k];
    if (k & 1) mL1 = fmaxf(mL1, x); else mL0 = fmaxf(mL0, x);
  }
  const float mL = g8max(fmaxf(mL0, mL1));
  const float msL = fmaxf(mL, -1e37f);
  const float nL = -msL * LOG2E;
  float sL0 = 0.f, sL1 = 0.f;
#pragma unroll
  for (int k = 0; k < K; ++k) {
    float e = __builtin_amdgcn_exp2f(__builtin_fmaf(a1R[k] + va[k], LOG2E, nL));
    if (k & 1) sL1 += e; else sL0 += e;
  }
  const float SL = g8sum(sL0 + sL1);

  // ---- load window 2: R stream (<=16 live) ----
  float vc[K];
#pragma unroll
  for (int k = 0; k < K; ++k) vc[k] = c2[8 * k * LP];
  __builtin_amdgcn_sched_barrier(0);

  // R bulk: lse_d[ si[ii][ii+d] + sc[ii+d][ii+w] ], d in [1,w-1]
  float mR0 = -INFINITY, mR1 = -INFINITY;
#pragma unroll
  for (int k = 0; k < K; ++k) {
    float x = c1R[k] + vc[k];
    if (k & 1) mR1 = fmaxf(mR1, x); else mR0 = fmaxf(mR0, x);
  }
  const float mR = g8max(fmaxf(mR0, mR1));
  const float msR = fmaxf(mR, -1e37f);
  const float nR = -msR * LOG2E;
  float sR0 = 0.f, sR1 = 0.f;
#pragma unroll
  for (int k = 0; k < K; ++k) {
    float e = __builtin_amdgcn_exp2f(__builtin_fmaf(c1R[k] + vc[k], LOG2E, nR));
    if (k & 1) sR1 += e; else sR0 += e;
  }
  const float SR = g8sum(sR0 + sR1);

  // ---- fix-up with group-local width-w terms ----
  const float t0 = il + sUp;   // cl j=0   : sc[ii][ii]=0 + si[ii+w][ii]
  const float tW = il + sLo;   // cr d=w   : si[ii][ii+w] + sc[ii+w][ii+w]=0
  const float msfL = fmaxf(fmaxf(mL, t0), -1e37f);
  const float SLf = SL * __builtin_amdgcn_exp2f((msL - msfL) * LOG2E)
                  + __builtin_amdgcn_exp2f((t0 - msfL) * LOG2E);
  const float clv = __builtin_amdgcn_logf(SLf) * LN2 + msfL;
  const float msfR = fmaxf(fmaxf(mR, tW), -1e37f);
  const float SRf = SR * __builtin_amdgcn_exp2f((msR - msfR) * LOG2E)
                  + __builtin_amdgcn_exp2f((tW - msfR) * LOG2E);
  float crv = __builtin_amdgcn_logf(SRf) * LN2 + msfR;
  if (rootBad) crv = -INFINITY;   // root-arity constraint

  // ---- stores (barrier placed by caller) ----
  if (writer) {
    tI[(ii + w) * LP + ii] = t0;
    tI[ii * LP + (ii + w)] = tW;
    tC[(ii + w) * LP + ii] = clv;
    tC[ii * LP + (ii + w)] = crv;
  }

  // ---- register appends (static slots; masked lane-select) ----
  // paR/a1R: new j=w -> slot w>>3 = K-1 (w&7!=0, lane w&7) or K (w&7==0, lane 0)
  const int wm7 = w & 7;
  const bool lnw = (lg == wm7) && (wm7 != 0);
  paR[K - 1] = lnw ? crv : paR[K - 1];
  a1R[K - 1] = lnw ? clv : a1R[K - 1];
  if constexpr (K < 16) {
    const bool z = (lg == 0) && (wm7 == 0);
    paR[K] = z ? crv : paR[K];
    a1R[K] = z ? clv : a1R[K];
  }
  // c1R: new d=w -> slot (w-1)>>3 = K-1, lane (w-1)&7
  const bool ln1 = (lg == ((w - 1) & 7));
  c1R[K - 1] = ln1 ? tW : c1R[K - 1];
}

__global__ __launch_bounds__(NT)
__attribute__((amdgpu_waves_per_eu(4, 4)))   // occupancy is LDS-bound at 4/EU:
void crf_inside(                             // free the VGPR budget to 128
    const float* __restrict__ scores, const int* __restrict__ mask,
    const int* __restrict__ target, float* __restrict__ acc) {
  extern __shared__ float lds[];
  float* tC = lds;          // complete spans (136 rows incl. guard)
  float* tI = lds + TC_SZ;  // incomplete spans
  const int b = blockIdx.x;
  const int t = threadIdx.x;
  const int lane = t & 63;
  const int wv = t >> 6;
  const int g = t >> 3;     // group index (0..127), 8 groups per wave
  const int lg = t & 7;     // lane in group
  const float* S = scores + (size_t)b * LL * LL;

  __shared__ float gred[NW];
  __shared__ int lred[NW];
  __shared__ float s_gold;
  __shared__ int s_len;

  // ---- lens + masked gold-score reduction (threads 0..127 hold data) ----
  int mv = 0; float gv = 0.f;
  if (t < LL) {
    mv = mask[b * LL + t] ? 1 : 0;
    if (mv) gv = S[t * LL + target[b * LL + t]];
  }
  int lm = mv; float lg_ = gv;
#pragma unroll
  for (int o = 32; o > 0; o >>= 1) {
    lm += __shfl_xor(lm, o, 64);
    lg_ += __shfl_xor(lg_, o, 64);
  }
  if (lane == 0) { lred[wv] = lm; gred[wv] = lg_; }

  // ---- init LDS (incl. guards) to -inf; diag of s_c = 0 ----
  for (int idx = t; idx < TC_SZ + TI_SZ; idx += NT) lds[idx] = -INFINITY;
  __syncthreads();
  if (t < LL) tC[t * LP + t] = 0.f;
  if (t == 0) {
    int l = 0; float gg = 0.f;
    for (int k = 0; k < NW; ++k) { l += lred[k]; gg += gred[k]; }
    s_len = l; s_gold = gg;
  }
  __syncthreads();
  const int len = s_len;

  // ---- register streams: -inf except paR[0] = diag 0 on lg==0 ----
  float paR[17], a1R[17], c1R[16];
#pragma unroll
  for (int k = 0; k < 17; ++k) { paR[k] = -INFINITY; a1R[k] = -INFINITY; }
#pragma unroll
  for (int k = 0; k < 16; ++k) c1R[k] = -INFINITY;
  if (lg == 0) paR[0] = 0.f;

  // ---- inside DP: one fused phase + one barrier per width ----
  for (int w = 1; w < LL; ++w) {
    const int ni = LL - w;
    const bool waveAct = (wv << 3) < ni;   // wave-uniform skip
    const int ii = min(g, ni - 1);         // clamped groups compute, no write
    const bool writer = (lg == 0) & (g < ni);
    const bool rootBad = (ii == 0) && (w != len);
    const int K = (w + 7) >> 3;
    if (waveAct) {
      switch (K) {
#define CASE_K(KK) case KK: fusedPhase<KK>(tC, tI, S, ii, w, lg, writer, rootBad, paR, a1R, c1R); break;
        CASE_K(1) CASE_K(2) CASE_K(3) CASE_K(4) CASE_K(5) CASE_K(6)
        CASE_K(7) CASE_K(8) CASE_K(9) CASE_K(10) CASE_K(11) CASE_K(12)
        CASE_K(13) CASE_K(14) CASE_K(15) CASE_K(16)
#undef CASE_K
      }
    }
    __syncthreads();
  }

  // ---- per-batch contribution ----
  if (t == 0) {
    float logZ = tC[len];  // sc[0][len]
    atomicAdd(&acc[0], logZ - s_gold);
    atomicAdd(&acc[1], (float)len);
  }
}

__global__ void zero_acc(float* acc) {
  acc[0] = 0.f;
  acc[1] = 0.f;
}

__global__ void finalize(const float* __restrict__ acc, float* __restrict__ out) {
  out[0] = acc[0] / acc[1];
}

extern "C" void kernel_launch(void* const* d_in, const int* in_sizes, int n_in,
                              void* d_out, int out_size, void* d_ws, size_t ws_size,
                              hipStream_t stream) {
  const float* scores = (const float*)d_in[0];
  const int* mask = (const int*)d_in[1];
  const int* target = (const int*)d_in[2];
  float* out = (float*)d_out;
  float* acc = (float*)d_ws;

  const int Bn = in_sizes[0] / (LL * LL);
  const size_t lds_bytes = (size_t)(TC_SZ + TI_SZ) * sizeof(float);  // 139584 B

  (void)hipFuncSetAttribute((const void*)crf_inside,
                            hipFuncAttributeMaxDynamicSharedMemorySize,
                            (int)lds_bytes);

  zero_acc<<<1, 1, 0, stream>>>(acc);
  crf_inside<<<Bn, NT, lds_bytes, stream>>>(scores, mask, target, acc);
  finalize<<<1, 1, 0, stream>>>(acc, out);
}